// Round 2
// baseline (189.351 us; speedup 1.0000x reference)
//
#include <hip/hip_runtime.h>

// DispNetC correlation volume: out[b,d,h,w] = mean_c L[b,c,h,w]*R[b,c,h,w-d]
// for w>=d, else 0.  f32 in / f32 out.
//
// R11 baseline: 52us/dispatch, delivery 2.6 TB/s, FETCH=64MiB (no over-fetch),
// VALU 7.5%, Mfma 1.1% -> latency/serialization bound, not bytes-bound.
// R12 (this): two orthogonal fixes to the delivery path:
//  1) XCD de-camping: blk->(b,h2) remap b=blk&7, h2=blk>>3. With round-robin
//     block->XCD dispatch the OLD map fixed h2&7 (addr bits [12:10]) per XCD
//     -> L2/LLC bin camping. New map: each XCD streams one b-slab with all 32
//     h2 phases -> low address bits fully exercised, 2MB contiguous window
//     covered per chunk per XCD.
//  2) Register-double-buffered prefetch: issue all 8 float4 loads for chunk
//     k+1 right after barrier A of chunk k into the other reg set; the stage
//     phase consumes the previous set with a counted vmcnt wait. Overlaps
//     ~9k cycles of LDS-transpose+MFMA with the next chunk's delivery instead
//     of idling the memory system between bursts. (+64 VGPR, stays <=128.)
// Compute = R6's hardware-verified 26-tile band MFMA, x2 h. Unchanged.

typedef __attribute__((ext_vector_type(8))) short short8;   // MFMA A/B frag
typedef __attribute__((ext_vector_type(4))) float floatx4;  // MFMA C/D frag

#define NB 8
#define NC 256
#define NH 64
#define NWD 128
#define ND 40
#define KC 64          // channels per chunk; 4 chunks
// s_waitcnt imm: vm[3:0] | exp[6:4]=7 | lgkm[11:8] | vm[5:4]@[15:14]
#define WCNT(vm, lgkm) (((vm) & 15) | (((vm) >> 4) << 14) | (7 << 4) | ((lgkm) << 8))

// LDS map (bytes):
//   Lbuf [hh][w][KC] u16 swizzled : 0      (32 KB)
//   Rbuf same                     : 32768  (32 KB)
//   scratch, per-wave 8*132 f32   : 65536 + wv*4224  (67.6 KB)
// total 133120 B -> 1 block/CU, 16 waves.

// Issue one chunk's 8 contiguous-1KB loads (2 units x 4 channel-rows) into dst.
#define ISSUE_CHUNK(ch, dst)                                                   \
  do {                                                                         \
    _Pragma("unroll")                                                          \
    for (int uu = 0; uu < 2; ++uu) {                                           \
      const int ug_  = wv * 2 + uu;                                            \
      const int arr_ = ug_ & 1;                                                \
      const int cq_  = ug_ >> 1;                                               \
      const int c0_  = (ch) * KC + cq_ * 4;                                    \
      const float* src_ = arr_ ? Rg : Lg;                                      \
      _Pragma("unroll")                                                        \
      for (int i = 0; i < 4; ++i) {                                            \
        const float* gp_ = src_ + gbase + (size_t)(c0_ + i) * HW               \
                         + (lane >> 5) * NWD + 4 * (lane & 31);                \
        dst[uu][i] = *(const float4*)gp_;                                      \
      }                                                                        \
    }                                                                          \
  } while (0)

__global__ __launch_bounds__(1024, 4) void corr_hpair(
    const float* __restrict__ Lg,
    const float* __restrict__ Rg,
    float* __restrict__ out)
{
  __shared__ __align__(16) unsigned char smem[65536 + 16 * 4224];

  const int blk  = blockIdx.x;
  const int b    = blk & 7;        // XCD-phase remap: round-robin dispatch ->
  const int h2   = blk >> 3;       // each XCD owns one b-slab, all h2 phases
  const int tid  = threadIdx.x;
  const int lane = tid & 63;
  const int wv   = tid >> 6;       // 0..15
  const int m    = lane & 15;
  const int q    = lane >> 4;

  const size_t HW    = (size_t)NH * NWD;
  const size_t gbase = (size_t)b * NC * HW + (size_t)(h2 * 2) * NWD;

  float* scr = (float*)(smem + 65536 + wv * 4224);   // [8][132] f32

  floatx4 acc[4];
  #pragma unroll
  for (int i = 0; i < 4; ++i) acc[i] = (floatx4){0.f, 0.f, 0.f, 0.f};

  float4 vA[2][4], vB[2][4];       // reg double-buffer for the staging loads
  ISSUE_CHUNK(0, vA);              // prologue: chunk 0 in flight

  #pragma unroll
  for (int chunk = 0; chunk < 4; ++chunk) {
    __syncthreads();  // barrier A: prev MFMA frag reads done before finals overwrite

    // ---- prefetch chunk+1 into the other reg set (flies under transpose+MFMA)
    if (chunk == 0) ISSUE_CHUNK(1, vB);
    else if (chunk == 1) ISSUE_CHUNK(2, vA);
    else if (chunk == 2) ISSUE_CHUNK(3, vB);

    // ---- stage from regs: 2 units/wave; unit = one array x 4 channels x both h
    {
      float4 (&vcur)[2][4] = (chunk & 1) ? vB : vA;
      #pragma unroll
      for (int uu = 0; uu < 2; ++uu) {
        const int ug  = wv * 2 + uu;     // 0..31
        const int arr = ug & 1;          // 0 = L, 1 = R
        const int cq  = ug >> 1;         // c-quad 0..15
        const int gu  = cq >> 1;         // 8-c group 0..7
        const int su  = cq & 1;          // which b64 half of the group

        // scratch write: row = 2*c' + hh, padded stride 132 (2-way free)
        #pragma unroll
        for (int i = 0; i < 4; ++i)
          *(float4*)(scr + (2 * i + (lane >> 5)) * 132 + 4 * (lane & 31)) =
              vcur[uu][i];
        __builtin_amdgcn_s_waitcnt(WCNT(63, 0));  // scratch visible to own wave

        // gather 4 c per (hh,w), pack bf16 (round-half-up), b64 to final
        unsigned short* fin = (unsigned short*)(smem + arr * 32768);
        #pragma unroll
        for (int t = 0; t < 4; ++t) {
          const int hh = t >> 1;
          const int w  = lane + (t & 1) * 64;
          float f[4];
          #pragma unroll
          for (int c1 = 0; c1 < 4; ++c1)
            f[c1] = scr[(2 * c1 + hh) * 132 + w];
          const unsigned int lo =
              ((__float_as_uint(f[0]) + 0x8000u) >> 16) |
              ((__float_as_uint(f[1]) + 0x8000u) & 0xFFFF0000u);
          const unsigned int hi =
              ((__float_as_uint(f[2]) + 0x8000u) >> 16) |
              ((__float_as_uint(f[3]) + 0x8000u) & 0xFFFF0000u);
          // u16 index: hh*8192 + w*64 + ((gu ^ (w&7))<<3) + 4*su  (swizzled)
          *(uint2*)(fin + hh * 8192 + w * 64 + ((gu ^ (w & 7)) << 3) + 4 * su) =
              make_uint2(lo, hi);
        }
        __builtin_amdgcn_s_waitcnt(WCNT(63, 0));  // gathers done before scratch reuse
      }
    }
    __syncthreads();

    // ---- MFMA: 52 instances (2h x 26 band tiles) over 16 waves ----
    const unsigned short* Lb = (const unsigned short*)smem;
    const unsigned short* Rb = (const unsigned short*)(smem + 32768);
    #pragma unroll
    for (int ks2 = 0; ks2 < 2; ++ks2) {        // two K=32 steps per chunk
      #pragma unroll
      for (int li = 0; li < 4; ++li) {
        const int inst = wv + (li << 4);
        if (inst >= 52) break;
        const int hh   = (inst >= 26) ? 1 : 0;
        const int tile = inst - hh * 26;
        const int i  = (tile < 8) ? tile : (tile < 15) ? tile - 8
                     : (tile < 21) ? tile - 15 : tile - 21;
        const int k  = (tile < 8) ? 0 : (tile < 15) ? 1 : (tile < 21) ? 2 : 3;
        const int j  = i + k;
        const int g  = ks2 * 4 + q;            // c = 32*ks2 + 8*q + e
        const int ra = 16 * i + m;             // w' row for A (from R)
        const int rb = 16 * j + m;             // w  col for B (from L)
        const short8 av =
            *(const short8*)(Rb + hh * 8192 + ra * 64 + ((g ^ (ra & 7)) << 3));
        const short8 bv =
            *(const short8*)(Lb + hh * 8192 + rb * 64 + ((g ^ (rb & 7)) << 3));
        acc[li] = __builtin_amdgcn_mfma_f32_16x16x32_bf16(av, bv, acc[li], 0, 0, 0);
      }
    }
  }

  // ---- epilogue: D layout col=lane&15 (w in tile j), row=q*4+r (w' in tile i) ----
  #pragma unroll
  for (int li = 0; li < 4; ++li) {
    const int inst = wv + (li << 4);
    if (inst >= 52) break;
    const int hh   = (inst >= 26) ? 1 : 0;
    const int tile = inst - hh * 26;
    const int i  = (tile < 8) ? tile : (tile < 15) ? tile - 8
                 : (tile < 21) ? tile - 15 : tile - 21;
    const int k  = (tile < 8) ? 0 : (tile < 15) ? 1 : (tile < 21) ? 2 : 3;
    const int j  = i + k;
    const int h  = h2 * 2 + hh;
    const int w  = 16 * j + m;
    #pragma unroll
    for (int r = 0; r < 4; ++r) {
      const int wp = 16 * i + q * 4 + r;
      const int d  = w - wp;
      if (d >= 0 && d < ND)
        out[(((size_t)b * ND + d) * NH + h) * NWD + w] = acc[li][r] * 0.00390625f;
    }
  }

  // ---- zero-fill the w<d triangle for both h (d_out poisoned each launch) ----
  for (int t = tid; t < 2 * ND * ND; t += 1024) {
    const int hh = (t >= ND * ND) ? 1 : 0;
    const int tt = t - hh * ND * ND;
    const int d  = tt / ND;
    const int w  = tt - d * ND;
    if (w < d)
      out[(((size_t)b * ND + d) * NH + (h2 * 2 + hh)) * NWD + w] = 0.0f;
  }
}

extern "C" void kernel_launch(void* const* d_in, const int* in_sizes, int n_in,
                              void* d_out, int out_size, void* d_ws, size_t ws_size,
                              hipStream_t stream) {
  corr_hpair<<<dim3(256), dim3(1024), 0, stream>>>(
      (const float*)d_in[0], (const float*)d_in[1], (float*)d_out);
}

// Round 3
// 183.383 us; speedup vs baseline: 1.0325x; 1.0325x over previous
//
#include <hip/hip_runtime.h>

// DispNetC correlation volume: out[b,d,h,w] = mean_c L[b,c,h,w]*R[b,c,h,w-d]
// for w>=d, else 0.  f32 in / f32 out.
//
// R11 baseline: 52us, delivery 2.6 TB/s, FETCH=64MiB, no over-fetch.
// R12 FAILED (92us): reg double-buffer via `(chunk&1)?vB:vA` reference select
//   -> arrays demoted to scratch (rule #20). WRITE_SIZE 10->141MB = exactly
//   the spill stores; LLC evicted, FETCH doubled. VGPR stayed 56 (tell-tale).
// R13 (this): same two mechanisms, spill-proofed:
//   1) XCD de-camping remap b=blk&7, h2=blk>>3 (kept from R12, unjudged there).
//   2) Register double-buffer with STATICALLY NAMED buffers: manual 4-chunk
//      unroll, every ISSUE/STAGE names vA or vB directly. No pointer selects,
//      no runtime indexing -> mem2reg keeps both buffers in VGPRs.
// Verification signature: VGPR ~115-125, WRITE_SIZE back to 10.2MB.
// Compute = R6's hardware-verified 26-tile band MFMA, x2 h. Unchanged.

typedef __attribute__((ext_vector_type(8))) short short8;   // MFMA A/B frag
typedef __attribute__((ext_vector_type(4))) float floatx4;  // MFMA C/D frag

#define NB 8
#define NC 256
#define NH 64
#define NWD 128
#define ND 40
#define KC 64          // channels per chunk; 4 chunks
// s_waitcnt imm: vm[3:0] | exp[6:4]=7 | lgkm[11:8] | vm[5:4]@[15:14]
#define WCNT(vm, lgkm) (((vm) & 15) | (((vm) >> 4) << 14) | (7 << 4) | ((lgkm) << 8))

// LDS map (bytes):
//   Lbuf [hh][w][KC] u16 swizzled : 0      (32 KB)
//   Rbuf same                     : 32768  (32 KB)
//   scratch, per-wave 8*132 f32   : 65536 + wv*4224  (67.6 KB)
// total 133120 B -> 1 block/CU, 16 waves.

// Issue one chunk's 8 contiguous-1KB loads (2 units x 4 channel-rows) into a
// STATICALLY NAMED register buffer `dst` (vA or vB -- never via a pointer).
#define ISSUE_CHUNK(ch, dst)                                                   \
  do {                                                                         \
    _Pragma("unroll")                                                          \
    for (int uu = 0; uu < 2; ++uu) {                                           \
      const int ug_  = wv * 2 + uu;                                            \
      const int arr_ = ug_ & 1;                                                \
      const int cq_  = ug_ >> 1;                                               \
      const int c0_  = (ch) * KC + cq_ * 4;                                    \
      const float* src_ = arr_ ? Rg : Lg;                                      \
      _Pragma("unroll")                                                        \
      for (int i = 0; i < 4; ++i) {                                            \
        const float* gp_ = src_ + gbase + (size_t)(c0_ + i) * HW               \
                         + (lane >> 5) * NWD + 4 * (lane & 31);                \
        dst[uu][i] = *(const float4*)gp_;                                      \
      }                                                                        \
    }                                                                          \
  } while (0)

// Transpose+pack one chunk from a STATICALLY NAMED register buffer into the
// swizzled bf16 LDS finals.
#define STAGE_FROM(buf)                                                        \
  do {                                                                         \
    _Pragma("unroll")                                                          \
    for (int uu = 0; uu < 2; ++uu) {                                           \
      const int ug  = wv * 2 + uu;     /* 0..31 */                             \
      const int arr = ug & 1;          /* 0 = L, 1 = R */                      \
      const int cq  = ug >> 1;         /* c-quad 0..15 */                      \
      const int gu  = cq >> 1;         /* 8-c group 0..7 */                    \
      const int su  = cq & 1;          /* which b64 half of the group */       \
      _Pragma("unroll")                                                        \
      for (int i = 0; i < 4; ++i)                                              \
        *(float4*)(scr + (2 * i + (lane >> 5)) * 132 + 4 * (lane & 31)) =      \
            buf[uu][i];                                                        \
      __builtin_amdgcn_s_waitcnt(WCNT(63, 0));                                 \
      unsigned short* fin = (unsigned short*)(smem + arr * 32768);             \
      _Pragma("unroll")                                                        \
      for (int t = 0; t < 4; ++t) {                                            \
        const int hh = t >> 1;                                                 \
        const int w  = lane + (t & 1) * 64;                                    \
        float f[4];                                                            \
        _Pragma("unroll")                                                      \
        for (int c1 = 0; c1 < 4; ++c1)                                         \
          f[c1] = scr[(2 * c1 + hh) * 132 + w];                                \
        const unsigned int lo =                                                \
            ((__float_as_uint(f[0]) + 0x8000u) >> 16) |                        \
            ((__float_as_uint(f[1]) + 0x8000u) & 0xFFFF0000u);                 \
        const unsigned int hi =                                                \
            ((__float_as_uint(f[2]) + 0x8000u) >> 16) |                        \
            ((__float_as_uint(f[3]) + 0x8000u) & 0xFFFF0000u);                 \
        *(uint2*)(fin + hh * 8192 + w * 64 + ((gu ^ (w & 7)) << 3) + 4 * su) = \
            make_uint2(lo, hi);                                                \
      }                                                                        \
      __builtin_amdgcn_s_waitcnt(WCNT(63, 0));                                 \
    }                                                                          \
  } while (0)

// 52 MFMA instances (2h x 26 band tiles) over 16 waves, two K=32 steps.
#define MFMA_CHUNK()                                                           \
  do {                                                                         \
    const unsigned short* Lb = (const unsigned short*)smem;                    \
    const unsigned short* Rb = (const unsigned short*)(smem + 32768);          \
    _Pragma("unroll")                                                          \
    for (int ks2 = 0; ks2 < 2; ++ks2) {                                        \
      _Pragma("unroll")                                                        \
      for (int li = 0; li < 4; ++li) {                                         \
        const int inst = wv + (li << 4);                                       \
        if (inst >= 52) break;                                                 \
        const int hh   = (inst >= 26) ? 1 : 0;                                 \
        const int tile = inst - hh * 26;                                       \
        const int i  = (tile < 8) ? tile : (tile < 15) ? tile - 8              \
                     : (tile < 21) ? tile - 15 : tile - 21;                    \
        const int k  = (tile < 8) ? 0 : (tile < 15) ? 1                        \
                     : (tile < 21) ? 2 : 3;                                    \
        const int j  = i + k;                                                  \
        const int g  = ks2 * 4 + q;                                            \
        const int ra = 16 * i + m;                                             \
        const int rb = 16 * j + m;                                             \
        const short8 av =                                                      \
            *(const short8*)(Rb + hh * 8192 + ra * 64 + ((g ^ (ra & 7)) << 3));\
        const short8 bv =                                                      \
            *(const short8*)(Lb + hh * 8192 + rb * 64 + ((g ^ (rb & 7)) << 3));\
        acc[li] =                                                              \
            __builtin_amdgcn_mfma_f32_16x16x32_bf16(av, bv, acc[li], 0, 0, 0); \
      }                                                                        \
    }                                                                          \
  } while (0)

__global__ __launch_bounds__(1024, 4) void corr_hpair(
    const float* __restrict__ Lg,
    const float* __restrict__ Rg,
    float* __restrict__ out)
{
  __shared__ __align__(16) unsigned char smem[65536 + 16 * 4224];

  const int blk  = blockIdx.x;
  const int b    = blk & 7;        // XCD-phase remap: round-robin dispatch ->
  const int h2   = blk >> 3;       // each XCD owns one b-slab, all h2 phases
  const int tid  = threadIdx.x;
  const int lane = tid & 63;
  const int wv   = tid >> 6;       // 0..15
  const int m    = lane & 15;
  const int q    = lane >> 4;

  const size_t HW    = (size_t)NH * NWD;
  const size_t gbase = (size_t)b * NC * HW + (size_t)(h2 * 2) * NWD;

  float* scr = (float*)(smem + 65536 + wv * 4224);   // [8][132] f32

  floatx4 acc[4];
  #pragma unroll
  for (int i = 0; i < 4; ++i) acc[i] = (floatx4){0.f, 0.f, 0.f, 0.f};

  float4 vA[2][4], vB[2][4];       // reg double-buffer, only ever named directly

  ISSUE_CHUNK(0, vA);              // prologue: chunk 0 in flight

  // ---- chunk 0 ----
  __syncthreads();
  ISSUE_CHUNK(1, vB);
  STAGE_FROM(vA);
  __syncthreads();
  MFMA_CHUNK();

  // ---- chunk 1 ----
  __syncthreads();
  ISSUE_CHUNK(2, vA);
  STAGE_FROM(vB);
  __syncthreads();
  MFMA_CHUNK();

  // ---- chunk 2 ----
  __syncthreads();
  ISSUE_CHUNK(3, vB);
  STAGE_FROM(vA);
  __syncthreads();
  MFMA_CHUNK();

  // ---- chunk 3 ----
  __syncthreads();
  STAGE_FROM(vB);
  __syncthreads();
  MFMA_CHUNK();

  // ---- epilogue: D layout col=lane&15 (w in tile j), row=q*4+r (w' in tile i) ----
  #pragma unroll
  for (int li = 0; li < 4; ++li) {
    const int inst = wv + (li << 4);
    if (inst >= 52) break;
    const int hh   = (inst >= 26) ? 1 : 0;
    const int tile = inst - hh * 26;
    const int i  = (tile < 8) ? tile : (tile < 15) ? tile - 8
                 : (tile < 21) ? tile - 15 : tile - 21;
    const int k  = (tile < 8) ? 0 : (tile < 15) ? 1 : (tile < 21) ? 2 : 3;
    const int j  = i + k;
    const int h  = h2 * 2 + hh;
    const int w  = 16 * j + m;
    #pragma unroll
    for (int r = 0; r < 4; ++r) {
      const int wp = 16 * i + q * 4 + r;
      const int d  = w - wp;
      if (d >= 0 && d < ND)
        out[(((size_t)b * ND + d) * NH + h) * NWD + w] = acc[li][r] * 0.00390625f;
    }
  }

  // ---- zero-fill the w<d triangle for both h (d_out poisoned each launch) ----
  for (int t = tid; t < 2 * ND * ND; t += 1024) {
    const int hh = (t >= ND * ND) ? 1 : 0;
    const int tt = t - hh * ND * ND;
    const int d  = tt / ND;
    const int w  = tt - d * ND;
    if (w < d)
      out[(((size_t)b * ND + d) * NH + (h2 * 2 + hh)) * NWD + w] = 0.0f;
  }
}

extern "C" void kernel_launch(void* const* d_in, const int* in_sizes, int n_in,
                              void* d_out, int out_size, void* d_ws, size_t ws_size,
                              hipStream_t stream) {
  corr_hpair<<<dim3(256), dim3(1024), 0, stream>>>(
      (const float*)d_in[0], (const float*)d_in[1], (float*)d_out);
}

// Round 5
// 149.704 us; speedup vs baseline: 1.2648x; 1.2250x over previous
//
#include <hip/hip_runtime.h>

// DispNetC correlation volume: out[b,d,h,w] = mean_c L[b,c,h,w]*R[b,c,h,w-d]
// for w>=d, else 0.  f32 in / f32 out.
//
// R11 baseline: 52us, delivery 2.6 TB/s, FETCH=64MiB, no over-fetch.
// R12/R13 FAILED (92/87us): reg-prefetch double buffer spilled to scratch
//   both times (VGPR stuck at 56, WRITE_SIZE 10->141MB = exact spill bytes).
//   Conclusion: stop using VGPRs for staging.
// R14: async staging via global_load_lds -- FAILED TO COMPILE: s_waitcnt
//   builtin needs a literal; `(s<15)?2:0` in a rolled loop is not one.
// R15 (this): R14 with the final iteration PEELED -- loop s=0..14 uses
//   constant vmcnt(2) (always exactly 2 newer loads in flight), peeled s=15
//   uses vmcnt(0). No design change otherwise:
//   - 16 sub-stages x 16c (both arrays); 3-buffer LDS ring (3x32KB) +
//     32KB bf16 finals = 128KB LDS, 1 block/CU, 16 waves.
//   - Raw s_barrier + counted vmcnt (never __syncthreads: that drains
//     vmcnt(0) and serializes). Issue sub s+2 after barrier s: loads fly
//     under 2 transpose phases + MFMA (~2k cyc >> ~900cy HBM latency).
//   - Transpose: 8x ds_read_b32 stride 1KB (2 lanes/bank = free) + bf16
//     pack + 1 ds_write_b128 at swizzled (gu^(tw&3)) slot.
//   - MFMA: 8 chunks x K=32, verified band-tile map.
//   - sched_barrier(0) brackets every s_barrier.

typedef __attribute__((ext_vector_type(8))) short short8;   // MFMA A/B frag
typedef __attribute__((ext_vector_type(4))) float floatx4;  // MFMA C/D frag

#define NB 8
#define NC 256
#define NH 64
#define NWD 128
#define ND 40
// s_waitcnt imm: vm[3:0] | exp[6:4]=7 | lgkm[11:8] | vm[5:4]@[15:14]
#define WCNT(vm, lgkm) (((vm) & 15) | (((vm) >> 4) << 14) | (7 << 4) | ((lgkm) << 8))

// async global->LDS, 16B per lane: global src per-lane, LDS dest wave-uniform
// base (HW writes base + lane*16).
__device__ __forceinline__ void gll16(const float* g, const float* l) {
  __builtin_amdgcn_global_load_lds(
      (const __attribute__((address_space(1))) unsigned int*)g,
      (__attribute__((address_space(3))) unsigned int*)l, 16, 0, 0);
}

// LDS map (bytes):
//   sbuf ring: 3 x 32768   f32 [arr][c'16][hh][w]          : 0
//   fin      : 32768       u16 [arr][hh][w][32c swizzled]  : 98304
// total 131072 B -> 1 block/CU, 16 waves.

// Issue sub-stage s (16 channels, both arrays) into ring buffer bi.
// 2 instrs/wave: rows r = 2wv, 2wv+1; r = arr*16 + c''. Each instr stages
// global rows (c, h0)+(c, h1) = 1KB contiguous -> LDS row r (1KB linear).
#define ISSUE_SUB(s, bi)                                                       \
  do {                                                                         \
    _Pragma("unroll")                                                          \
    for (int j_ = 0; j_ < 2; ++j_) {                                           \
      const int r_ = wv * 2 + j_;                                              \
      const int c_ = (s) * 16 + (r_ & 15);                                     \
      const float* g_ = ((r_ >> 4) ? Rg : Lg) + gbase + (size_t)c_ * HW;       \
      gll16(g_ + lane * 4, sbuf + (bi) * 8192 + r_ * 256);                     \
    }                                                                          \
  } while (0)

// Transpose sub-stage s from ring buffer bi into fin.
// Thread role: col = tid>>1 -> (tarr,thh,tw); thalf = tid&1 -> 8-c group.
// 8x ds_read_b32 stride 1KB (bank = tw%32, 2 lanes/bank = free), pack bf16
// round-half-up, one b128 write at swizzled (gu^(tw&3)) slot.
#define TRANSPOSE_SUB(s, bi)                                                   \
  do {                                                                         \
    const float* sb_ = sbuf + (bi) * 8192 + tarr * 4096 + thalf * 2048         \
                     + thh * 128 + tw;                                         \
    float f_[8];                                                               \
    _Pragma("unroll")                                                          \
    for (int i_ = 0; i_ < 8; ++i_) f_[i_] = sb_[i_ * 256];                     \
    unsigned int u_[4];                                                        \
    _Pragma("unroll")                                                          \
    for (int i_ = 0; i_ < 4; ++i_)                                             \
      u_[i_] = ((__float_as_uint(f_[2 * i_]) + 0x8000u) >> 16) |               \
               ((__float_as_uint(f_[2 * i_ + 1]) + 0x8000u) & 0xFFFF0000u);    \
    const int gu_ = ((s) & 1) * 2 + thalf;                                     \
    *(uint4*)(fin + tarr * 8192 + thh * 4096 + tw * 32 +                       \
              ((gu_ ^ (tw & 3)) << 3)) =                                       \
        make_uint4(u_[0], u_[1], u_[2], u_[3]);                                \
  } while (0)

// 52 MFMA instances (2h x 26 band tiles) over 16 waves, one K=32 step.
#define MFMA_CHUNK32()                                                         \
  do {                                                                         \
    const unsigned short* Lb = fin;                                            \
    const unsigned short* Rb = fin + 8192;                                     \
    _Pragma("unroll")                                                          \
    for (int li = 0; li < 4; ++li) {                                           \
      const int inst = wv + (li << 4);                                         \
      if (inst >= 52) break;                                                   \
      const int hh   = (inst >= 26) ? 1 : 0;                                   \
      const int tile = inst - hh * 26;                                         \
      const int i  = (tile < 8) ? tile : (tile < 15) ? tile - 8                \
                   : (tile < 21) ? tile - 15 : tile - 21;                      \
      const int k  = (tile < 8) ? 0 : (tile < 15) ? 1                          \
                   : (tile < 21) ? 2 : 3;                                      \
      const int j  = i + k;                                                    \
      const int ra = 16 * i + m;                                               \
      const int rb = 16 * j + m;                                               \
      const short8 av =                                                        \
          *(const short8*)(Rb + hh * 4096 + ra * 32 + ((q ^ (ra & 3)) << 3));  \
      const short8 bv =                                                        \
          *(const short8*)(Lb + hh * 4096 + rb * 32 + ((q ^ (rb & 3)) << 3));  \
      acc[li] =                                                                \
          __builtin_amdgcn_mfma_f32_16x16x32_bf16(av, bv, acc[li], 0, 0, 0);   \
    }                                                                          \
  } while (0)

__global__ __launch_bounds__(1024, 4) void corr_async(
    const float* __restrict__ Lg,
    const float* __restrict__ Rg,
    float* __restrict__ out)
{
  __shared__ __align__(16) unsigned char smem[131072];
  float* sbuf = (float*)smem;                                // 3 x 8192 f32
  unsigned short* fin = (unsigned short*)(smem + 98304);     // 16384 u16

  const int blk  = blockIdx.x;
  const int b    = blk & 7;        // XCD de-camping remap (R12, kept)
  const int h2   = blk >> 3;
  const int tid  = threadIdx.x;
  const int lane = tid & 63;
  const int wv   = tid >> 6;       // 0..15
  const int m    = lane & 15;
  const int q    = lane >> 4;

  // transpose thread role
  const int tarr  = tid >> 9;
  const int thh   = (tid >> 8) & 1;
  const int tw    = (tid >> 1) & 127;
  const int thalf = tid & 1;

  const size_t HW    = (size_t)NH * NWD;
  const size_t gbase = (size_t)b * NC * HW + (size_t)(h2 * 2) * NWD;

  floatx4 acc[4];
  #pragma unroll
  for (int i = 0; i < 4; ++i) acc[i] = (floatx4){0.f, 0.f, 0.f, 0.f};

  // prologue: subs 0,1 in flight (4 outstanding vm ops/wave)
  ISSUE_SUB(0, 0);
  ISSUE_SUB(1, 1);

  for (int s = 0; s < 15; ++s) {
    // own sub-s loads complete (leave the 2 newer in flight), then barrier:
    // all waves' sub-s staging visible AND all transpose(s-1) reads retired.
    __builtin_amdgcn_s_waitcnt(WCNT(2, 15));
    __builtin_amdgcn_s_barrier();
    __builtin_amdgcn_sched_barrier(0);

    if (s < 14) ISSUE_SUB(s + 2, (s + 2) % 3);   // overwrites buf read at s-1: safe
    TRANSPOSE_SUB(s, s % 3);

    if (s & 1) {   // chunk boundary: fin (32c) complete -> MFMA
      __builtin_amdgcn_s_waitcnt(WCNT(63, 0));   // fin writes visible (lgkm only!)
      __builtin_amdgcn_s_barrier();
      __builtin_amdgcn_sched_barrier(0);
      MFMA_CHUNK32();
      __builtin_amdgcn_s_barrier();              // fin free for next chunk
      __builtin_amdgcn_sched_barrier(0);
    }
  }

  // ---- peeled s = 15: no loads in flight beyond our own last sub ----
  __builtin_amdgcn_s_waitcnt(WCNT(0, 15));
  __builtin_amdgcn_s_barrier();
  __builtin_amdgcn_sched_barrier(0);
  TRANSPOSE_SUB(15, 0);                          // 15 % 3 == 0
  __builtin_amdgcn_s_waitcnt(WCNT(63, 0));       // fin writes visible
  __builtin_amdgcn_s_barrier();
  __builtin_amdgcn_sched_barrier(0);
  MFMA_CHUNK32();

  // ---- epilogue: D layout col=lane&15 (w in tile j), row=q*4+r (w' in tile i) ----
  #pragma unroll
  for (int li = 0; li < 4; ++li) {
    const int inst = wv + (li << 4);
    if (inst >= 52) break;
    const int hh   = (inst >= 26) ? 1 : 0;
    const int tile = inst - hh * 26;
    const int i  = (tile < 8) ? tile : (tile < 15) ? tile - 8
                 : (tile < 21) ? tile - 15 : tile - 21;
    const int k  = (tile < 8) ? 0 : (tile < 15) ? 1 : (tile < 21) ? 2 : 3;
    const int j  = i + k;
    const int h  = h2 * 2 + hh;
    const int w  = 16 * j + m;
    #pragma unroll
    for (int r = 0; r < 4; ++r) {
      const int wp = 16 * i + q * 4 + r;
      const int d  = w - wp;
      if (d >= 0 && d < ND)
        out[(((size_t)b * ND + d) * NH + h) * NWD + w] = acc[li][r] * 0.00390625f;
    }
  }

  // ---- zero-fill the w<d triangle for both h (d_out poisoned each launch) ----
  for (int t = tid; t < 2 * ND * ND; t += 1024) {
    const int hh = (t >= ND * ND) ? 1 : 0;
    const int tt = t - hh * ND * ND;
    const int d  = tt / ND;
    const int w  = tt - d * ND;
    if (w < d)
      out[(((size_t)b * ND + d) * NH + (h2 * 2 + hh)) * NWD + w] = 0.0f;
  }
}

extern "C" void kernel_launch(void* const* d_in, const int* in_sizes, int n_in,
                              void* d_out, int out_size, void* d_ws, size_t ws_size,
                              hipStream_t stream) {
  corr_async<<<dim3(256), dim3(1024), 0, stream>>>(
      (const float*)d_in[0], (const float*)d_in[1], (float*)d_out);
}